// Round 11
// baseline (301.276 us; speedup 1.0000x reference)
//
#include <hip/hip_runtime.h>
#include <cstdint>

// ---------------------------------------------------------------------------
// AnaphoricityScorer: scores = rough + FFNN([a, b, a*b, pw] @ W1 -> leaky -> W_out)
// Factorized: h = Ha[batch] + Hb[idx] + (a*b|pw)@W1cd + b1
// R11: all GEMMs on the wave-independent pre-packed template (R10-verified
//   fragment layout: tile[rt][kc][lane][8], lane=(row%16)+16*((k%32)>>3)).
//   k_gt<WR,EPI>: WR row-waves x 2 col-waves; col-waves share A frags (L1),
//   row-waves share B frags (L1) -> per-CU L2 traffic per K-step 48KB->32KB
//   (R10 was L2-BW-bound: needed ~103-155 B/cyc vs 56 available).
//   W1 fully packed to BtAll[64ct][98kc]; mentions packed by k_packM;
//   k_pairs rewritten: 1 block per 16-pair tile, coalesced 1KB writes,
//   L1-resident gathers. No LDS, no barriers in any GEMM.
// ---------------------------------------------------------------------------

typedef short short8 __attribute__((ext_vector_type(8)));
typedef float f32x4 __attribute__((ext_vector_type(4)));

#define BT_STRIDE 100352  // 98 kc * 1024 B per 16-col W1 tile
#define MT_STRIDE 32768   // 32 kc * 1024 B per 16-row mention tile
#define PT_STRIDE 34816   // 34 kc * 1024 B per 16-row pair tile

static __device__ __forceinline__ unsigned short f2bf(float x) {
  union { float f; unsigned u; } v; v.f = x;
  unsigned r = v.u + 0x7fffu + ((v.u >> 16) & 1u);  // RNE
  return (unsigned short)(r >> 16);
}
static __device__ __forceinline__ float bf2f(unsigned short u) {
  union { unsigned u; float f; } v; v.u = ((unsigned)u) << 16;
  return v.f;
}

// W1 [3136][1024] f32 -> BtAll [64 ct][98 kc][64 lane][8] bf16 (R10-verified map)
__global__ void k_packW(const float* __restrict__ W1, unsigned short* __restrict__ BtAll) {
  __shared__ float t[64][65];
  int k0 = blockIdx.x * 64, n0 = blockIdx.y * 64;
  int c = threadIdx.x & 63, r4 = threadIdx.x >> 6;
#pragma unroll
  for (int rr = 0; rr < 16; ++rr) {
    int r = rr * 4 + r4;
    t[r][c] = W1[(size_t)(k0 + r) * 1024 + n0 + c];  // t[k-local][col-local]
  }
  __syncthreads();
#pragma unroll
  for (int qq = 0; qq < 2; ++qq) {
    int q = threadIdx.x * 2 + qq;   // 0..511
    int cc = q >> 3, rg = q & 7;    // col-local, k-octet
    short8 v;
#pragma unroll
    for (int e = 0; e < 8; ++e) v[e] = (short)f2bf(t[rg * 8 + e][cc]);
    int ct = (n0 + cc) >> 4;
    int kc = (k0 >> 5) + (rg >> 2);
    int ln = (cc & 15) + ((rg & 3) << 4);
    *(short8*)((char*)BtAll + (size_t)ct * BT_STRIDE + kc * 1024 + ln * 16) = v;
  }
}

// f32 -> bf16 row-major (sources for k_pairs)
__global__ void k_cvt(const float* __restrict__ s, unsigned short* __restrict__ d, int n4) {
  int i = blockIdx.x * 256 + threadIdx.x;
  if (i < n4) {
    float4 v = ((const float4*)s)[i];
    ushort4 o; o.x = f2bf(v.x); o.y = f2bf(v.y); o.z = f2bf(v.z); o.w = f2bf(v.w);
    ((ushort4*)d)[i] = o;
  }
}

// mentions (am rows -> rt 0..63, allm rows -> rt 64..575) -> Mt fragment tiles
__global__ void k_packM(const float* __restrict__ am, const float* __restrict__ allm,
                        unsigned short* __restrict__ Mt) {
  int rt = blockIdx.x, t = threadIdx.x;
  const float* S = (rt < 64) ? (am + (size_t)rt * 16 * 1024)
                             : (allm + (size_t)(rt - 64) * 16 * 1024);
  int pf = t & 15, oct = (t >> 4) & 3, kcl = t >> 6;
  const float* row = S + (size_t)pf * 1024;
  char* dst = (char*)Mt + (size_t)rt * MT_STRIDE + (t & 63) * 16;
#pragma unroll
  for (int pass = 0; pass < 8; ++pass) {
    int kc = pass * 4 + kcl;
    int k = kc * 32 + oct * 8;
    float4 v0 = *(const float4*)(row + k);
    float4 v1 = *(const float4*)(row + k + 4);
    short8 o;
    o[0] = (short)f2bf(v0.x); o[1] = (short)f2bf(v0.y);
    o[2] = (short)f2bf(v0.z); o[3] = (short)f2bf(v0.w);
    o[4] = (short)f2bf(v1.x); o[5] = (short)f2bf(v1.y);
    o[6] = (short)f2bf(v1.z); o[7] = (short)f2bf(v1.w);
    *(short8*)(dst + kc * 1024) = o;
  }
}

// Pair tiles: block = one rt (16 pairs). Coalesced 1KB slab writes; gathers
// L1-resident (16 rows x 2KB). kc 0..31 = a*b, kc 32..33 = pw.
__global__ void k_pairs(const unsigned short* __restrict__ Abm,
                        const unsigned short* __restrict__ Aball,
                        const float* __restrict__ pw, const int* __restrict__ idx,
                        unsigned short* __restrict__ Pt) {
  __shared__ int g16[16];
  int rt = blockIdx.x, t = threadIdx.x;
  if (t < 16) g16[t] = idx[rt * 16 + t];
  __syncthreads();
  int pf = t & 15, oct = (t >> 4) & 3, kcl = t >> 6;
  int p = rt * 16 + pf;
  const unsigned short* arow = Abm + (size_t)(p / 50) * 1024;
  const unsigned short* brow = Aball + (size_t)g16[pf] * 1024;
  char* dst = (char*)Pt + (size_t)rt * PT_STRIDE + (t & 63) * 16;
#pragma unroll
  for (int pass = 0; pass < 8; ++pass) {
    int kc = pass * 4 + kcl;
    int k = kc * 32 + oct * 8;
    short8 a8 = *(const short8*)(arow + k);
    short8 b8 = *(const short8*)(brow + k);
    short8 o;
#pragma unroll
    for (int e = 0; e < 8; ++e)
      o[e] = (short)f2bf(bf2f((unsigned short)a8[e]) * bf2f((unsigned short)b8[e]));
    *(short8*)(dst + kc * 1024) = o;
  }
  if (t < 128) {
    int kc = 32 + (t >> 6);
    int kpw = (t >> 6) * 32 + oct * 8;
    const float* prow = pw + (size_t)p * 64;
    float4 v0 = *(const float4*)(prow + kpw);
    float4 v1 = *(const float4*)(prow + kpw + 4);
    short8 o;
    o[0] = (short)f2bf(v0.x); o[1] = (short)f2bf(v0.y);
    o[2] = (short)f2bf(v0.z); o[3] = (short)f2bf(v0.w);
    o[4] = (short)f2bf(v1.x); o[5] = (short)f2bf(v1.y);
    o[6] = (short)f2bf(v1.z); o[7] = (short)f2bf(v1.w);
    *(short8*)(dst + kc * 1024) = o;
  }
}

// Wave-independent pre-packed GEMM. WR row-waves x 2 col-waves; block covers
// (WR*64) rows x 256 cols; grid = (rows/(WR*64)) * 4, XCD-chunked swizzle.
// EPI=0: C[rows][1024] f32 store. EPI=1: fused scorer epilogue -> partial.
template <int WR, int EPI>
__global__ __launch_bounds__(WR * 128, 2) void k_gt(
    const unsigned short* __restrict__ At, int at_rt0, int a_stride, int nkc,
    const unsigned short* __restrict__ BtAll, int kcoff,
    float* __restrict__ C, float* __restrict__ partial,
    const float* __restrict__ Ha, const float* __restrict__ Hb,
    const float* __restrict__ b1, const float* __restrict__ Wout,
    const int* __restrict__ idx) {
  int tid = threadIdx.x, lane = tid & 63, wave = tid >> 6;
  int wr = wave >> 1, wc = wave & 1;
  int llo = lane & 15, lhi = lane >> 4;
  int cpx = gridDim.x >> 3;
  int orig = (blockIdx.x & 7) * cpx + (blockIdx.x >> 3);
  int x = orig >> 2, y = orig & 3;
  int row0 = x * (WR * 64) + wr * 64;
  int n0w = y * 256 + wc * 128;
  const char* pam[4];
  const char* pbn[8];
#pragma unroll
  for (int m = 0; m < 4; ++m)
    pam[m] = (const char*)At + (size_t)(at_rt0 + (row0 >> 4) + m) * a_stride + lane * 16;
#pragma unroll
  for (int n = 0; n < 8; ++n)
    pbn[n] = (const char*)BtAll + (size_t)((n0w >> 4) + n) * BT_STRIDE +
             (size_t)kcoff * 1024 + lane * 16;

  f32x4 acc[4][8] = {};
  short8 aA[4], bA[8], aB[4], bB[8];
#pragma unroll
  for (int m = 0; m < 4; ++m) aA[m] = *(const short8*)(pam[m]);
#pragma unroll
  for (int n = 0; n < 8; ++n) bA[n] = *(const short8*)(pbn[n]);
  for (int kt = 0; kt < nkc; kt += 2) {
#pragma unroll
    for (int m = 0; m < 4; ++m)
      aB[m] = *(const short8*)(pam[m] + (kt + 1) * 1024);
#pragma unroll
    for (int n = 0; n < 8; ++n)
      bB[n] = *(const short8*)(pbn[n] + (kt + 1) * 1024);
#pragma unroll
    for (int m = 0; m < 4; ++m)
#pragma unroll
      for (int n = 0; n < 8; ++n)
        acc[m][n] = __builtin_amdgcn_mfma_f32_16x16x32_bf16(aA[m], bA[n], acc[m][n], 0, 0, 0);
    if (kt + 2 < nkc) {
#pragma unroll
      for (int m = 0; m < 4; ++m)
        aA[m] = *(const short8*)(pam[m] + (kt + 2) * 1024);
#pragma unroll
      for (int n = 0; n < 8; ++n)
        bA[n] = *(const short8*)(pbn[n] + (kt + 2) * 1024);
    }
#pragma unroll
    for (int m = 0; m < 4; ++m)
#pragma unroll
      for (int n = 0; n < 8; ++n)
        acc[m][n] = __builtin_amdgcn_mfma_f32_16x16x32_bf16(aB[m], bB[n], acc[m][n], 0, 0, 0);
  }

  if (EPI == 0) {
#pragma unroll
    for (int m = 0; m < 4; ++m)
#pragma unroll
      for (int i = 0; i < 4; ++i) {
        int row = row0 + m * 16 + lhi * 4 + i;
#pragma unroll
        for (int n = 0; n < 8; ++n)
          C[(size_t)row * 1024 + n0w + n * 16 + llo] = acc[m][n][i];
      }
  } else {
    float b1v[8], wov[8];
    int coln[8];
#pragma unroll
    for (int n = 0; n < 8; ++n) {
      coln[n] = n0w + n * 16 + llo;
      b1v[n] = b1[coln[n]];
      wov[n] = Wout[coln[n]];
    }
    int chunk = n0w >> 6;  // y*4 + wc*2
#pragma unroll
    for (int m = 0; m < 4; ++m)
#pragma unroll
      for (int i = 0; i < 4; ++i) {
        int p = row0 + m * 16 + lhi * 4 + i;
        int bb = p / 50;
        int gg = idx[p];
        const float* Har = Ha + (size_t)bb * 1024;
        const float* Hbr = Hb + (size_t)gg * 1024;
        float s0 = 0.f, s1 = 0.f;
#pragma unroll
        for (int n = 0; n < 4; ++n) {
          float h = acc[m][n][i] + Har[coln[n]] + Hbr[coln[n]] + b1v[n];
          h = h > 0.f ? h : 0.01f * h;
          s0 += h * wov[n];
        }
#pragma unroll
        for (int n = 4; n < 8; ++n) {
          float h = acc[m][n][i] + Har[coln[n]] + Hbr[coln[n]] + b1v[n];
          h = h > 0.f ? h : 0.01f * h;
          s1 += h * wov[n];
        }
        s0 += __shfl_xor(s0, 1, 64);
        s0 += __shfl_xor(s0, 2, 64);
        s0 += __shfl_xor(s0, 4, 64);
        s0 += __shfl_xor(s0, 8, 64);
        s1 += __shfl_xor(s1, 1, 64);
        s1 += __shfl_xor(s1, 2, 64);
        s1 += __shfl_xor(s1, 4, 64);
        s1 += __shfl_xor(s1, 8, 64);
        if (llo == 0) {
          partial[(size_t)p * 16 + chunk + 0] = s0;
          partial[(size_t)p * 16 + chunk + 1] = s1;
        }
      }
  }
}

__global__ void k_final(const float* __restrict__ partial, const float* __restrict__ rough,
                        const float* __restrict__ bout, float* __restrict__ out) {
  int t = blockIdx.x * 256 + threadIdx.x;
  if (t < 51200) {
    float s = rough[t] + bout[0];
    const float* pp = partial + (size_t)t * 16;
#pragma unroll
    for (int c = 0; c < 16; ++c) s += pp[c];
    out[(size_t)(t / 50) * 51 + 1 + (t % 50)] = s;
  }
  if (t < 1024) out[(size_t)t * 51] = 1e-7f;
}

extern "C" void kernel_launch(void* const* d_in, const int* in_sizes, int n_in,
                              void* d_out, int out_size, void* d_ws, size_t ws_size,
                              hipStream_t stream) {
  (void)in_sizes; (void)n_in; (void)out_size;
  const float* allm  = (const float*)d_in[0];  // [8192][1024]
  const float* am    = (const float*)d_in[1];  // [1024][1024]
  const float* pw    = (const float*)d_in[2];  // [1024][50][64]
  const float* rough = (const float*)d_in[3];  // [1024][50]
  const float* W1    = (const float*)d_in[4];  // [3136][1024]
  const float* b1    = (const float*)d_in[5];  // [1024]
  const float* Wout  = (const float*)d_in[6];  // [1024]
  const float* bout  = (const float*)d_in[7];  // [1]
  const int*   idx   = (const int*)d_in[8];    // [1024][50]
  float* out = (float*)d_out;                  // [1024][51]

  char* w = (char*)d_ws;
  unsigned short* BtAll = (unsigned short*)w; w += (size_t)64 * BT_STRIDE;
  unsigned short* Mt    = (unsigned short*)w; w += (size_t)576 * MT_STRIDE;
  unsigned short* Abm   = (unsigned short*)w; w += (size_t)1024 * 1024 * 2;
  unsigned short* Aball = (unsigned short*)w; w += (size_t)8192 * 1024 * 2;
  unsigned short* Pt    = (unsigned short*)w; w += (size_t)3200 * PT_STRIDE;
  float* Ha             = (float*)w;          w += (size_t)1024 * 1024 * 4;
  float* Hb             = (float*)w;          w += (size_t)8192 * 1024 * 4;
  float* part           = (float*)w;          w += (size_t)51200 * 16 * 4;
  size_t need = (size_t)(w - (char*)d_ws);
  if (ws_size < need) return;

  k_packW<<<dim3(49, 16), 256, 0, stream>>>(W1, BtAll);
  k_cvt<<<dim3(1024), 256, 0, stream>>>(am, Abm, 1024 * 1024 / 4);
  k_cvt<<<dim3(8192), 256, 0, stream>>>(allm, Aball, 8192 * 1024 / 4);
  k_packM<<<dim3(576), 256, 0, stream>>>(am, allm, Mt);
  k_pairs<<<dim3(3200), 256, 0, stream>>>(Abm, Aball, pw, idx, Pt);
  // Ha: 1024 rows, WR=1 -> 16 x * 4 y = 64 blocks
  k_gt<1, 0><<<dim3(64), 128, 0, stream>>>(Mt, 0, MT_STRIDE, 32, BtAll, 0,
                                           Ha, nullptr, nullptr, nullptr,
                                           nullptr, nullptr, nullptr);
  // Hb: 8192 rows, WR=2 -> 64 x * 4 y = 256 blocks
  k_gt<2, 0><<<dim3(256), 256, 0, stream>>>(Mt, 64, MT_STRIDE, 32, BtAll, 32,
                                            Hb, nullptr, nullptr, nullptr,
                                            nullptr, nullptr, nullptr);
  // main: 51200 rows, WR=4 -> 200 x * 4 y = 800 blocks
  k_gt<4, 1><<<dim3(800), 512, 0, stream>>>(Pt, 0, PT_STRIDE, 34, BtAll, 64,
                                            nullptr, part, Ha, Hb, b1, Wout, idx);
  k_final<<<dim3(200), 256, 0, stream>>>(part, rough, bout, out);
}

// Round 12
// 256.440 us; speedup vs baseline: 1.1748x; 1.1748x over previous
//
#include <hip/hip_runtime.h>
#include <cstdint>

// ---------------------------------------------------------------------------
// AnaphoricityScorer: scores = rough + FFNN([a, b, a*b, pw] @ W1 -> leaky -> W_out)
// Factorized: h = Ha[batch] + Hb[idx] + (a*b|pw)@W1cd + b1
// R12: consolidation of proven pieces.
//   - main GEMM: byte-exact R10 k_maint structure (153us, MfmaUtil 32%):
//     4 waves/block, each 64 rows, SHARED 128-col B panel, pre-packed frags,
//     2-deep ping-pong, no LDS/barriers. (R11's 8-wave variant regressed:
//     VGPR-fill bandwidth is the binding resource; L1 sharing doesn't cut it.)
//   - Ha+Hb fused into ONE launch of the same template over Hab[9216][1024]
//     (rows 0..8191 = all_mentions @ W1[1024:2048], 8192.. = batch @ W1[0:1024])
//   - R11's coalesced k_pairs/k_packM kept; Mt ordered allm-first.
// ---------------------------------------------------------------------------

typedef short short8 __attribute__((ext_vector_type(8)));
typedef float f32x4 __attribute__((ext_vector_type(4)));

#define BT_STRIDE 100352  // 98 kc * 1024 B per 16-col W1 tile
#define MT_STRIDE 32768   // 32 kc * 1024 B per 16-row mention tile
#define PT_STRIDE 34816   // 34 kc * 1024 B per 16-row pair tile

static __device__ __forceinline__ unsigned short f2bf(float x) {
  union { float f; unsigned u; } v; v.f = x;
  unsigned r = v.u + 0x7fffu + ((v.u >> 16) & 1u);  // RNE
  return (unsigned short)(r >> 16);
}
static __device__ __forceinline__ float bf2f(unsigned short u) {
  union { unsigned u; float f; } v; v.u = ((unsigned)u) << 16;
  return v.f;
}

// W1 [3136][1024] f32 -> BtAll [64 ct][98 kc][64 lane][8] bf16
__global__ void k_packW(const float* __restrict__ W1, unsigned short* __restrict__ BtAll) {
  __shared__ float t[64][65];
  int k0 = blockIdx.x * 64, n0 = blockIdx.y * 64;
  int c = threadIdx.x & 63, r4 = threadIdx.x >> 6;
#pragma unroll
  for (int rr = 0; rr < 16; ++rr) {
    int r = rr * 4 + r4;
    t[r][c] = W1[(size_t)(k0 + r) * 1024 + n0 + c];
  }
  __syncthreads();
#pragma unroll
  for (int qq = 0; qq < 2; ++qq) {
    int q = threadIdx.x * 2 + qq;
    int cc = q >> 3, rg = q & 7;
    short8 v;
#pragma unroll
    for (int e = 0; e < 8; ++e) v[e] = (short)f2bf(t[rg * 8 + e][cc]);
    int ct = (n0 + cc) >> 4;
    int kc = (k0 >> 5) + (rg >> 2);
    int ln = (cc & 15) + ((rg & 3) << 4);
    *(short8*)((char*)BtAll + (size_t)ct * BT_STRIDE + kc * 1024 + ln * 16) = v;
  }
}

__global__ void k_cvt(const float* __restrict__ s, unsigned short* __restrict__ d, int n4) {
  int i = blockIdx.x * 256 + threadIdx.x;
  if (i < n4) {
    float4 v = ((const float4*)s)[i];
    ushort4 o; o.x = f2bf(v.x); o.y = f2bf(v.y); o.z = f2bf(v.z); o.w = f2bf(v.w);
    ((ushort4*)d)[i] = o;
  }
}

// mentions -> Mt fragment tiles; rt 0..511 = allm rows, rt 512..575 = am rows.
__global__ void k_packM(const float* __restrict__ am, const float* __restrict__ allm,
                        unsigned short* __restrict__ Mt) {
  int rt = blockIdx.x, t = threadIdx.x;
  const float* S = (rt < 512) ? (allm + (size_t)rt * 16 * 1024)
                              : (am + (size_t)(rt - 512) * 16 * 1024);
  int pf = t & 15, oct = (t >> 4) & 3, kcl = t >> 6;
  const float* row = S + (size_t)pf * 1024;
  char* dst = (char*)Mt + (size_t)rt * MT_STRIDE + (t & 63) * 16;
#pragma unroll
  for (int pass = 0; pass < 8; ++pass) {
    int kc = pass * 4 + kcl;
    int k = kc * 32 + oct * 8;
    float4 v0 = *(const float4*)(row + k);
    float4 v1 = *(const float4*)(row + k + 4);
    short8 o;
    o[0] = (short)f2bf(v0.x); o[1] = (short)f2bf(v0.y);
    o[2] = (short)f2bf(v0.z); o[3] = (short)f2bf(v0.w);
    o[4] = (short)f2bf(v1.x); o[5] = (short)f2bf(v1.y);
    o[6] = (short)f2bf(v1.z); o[7] = (short)f2bf(v1.w);
    *(short8*)(dst + kc * 1024) = o;
  }
}

// Pair tiles: block = one rt (16 pairs), coalesced 1KB slab writes.
__global__ void k_pairs(const unsigned short* __restrict__ Abm,
                        const unsigned short* __restrict__ Aball,
                        const float* __restrict__ pw, const int* __restrict__ idx,
                        unsigned short* __restrict__ Pt) {
  __shared__ int g16[16];
  int rt = blockIdx.x, t = threadIdx.x;
  if (t < 16) g16[t] = idx[rt * 16 + t];
  __syncthreads();
  int pf = t & 15, oct = (t >> 4) & 3, kcl = t >> 6;
  int p = rt * 16 + pf;
  const unsigned short* arow = Abm + (size_t)(p / 50) * 1024;
  const unsigned short* brow = Aball + (size_t)g16[pf] * 1024;
  char* dst = (char*)Pt + (size_t)rt * PT_STRIDE + (t & 63) * 16;
#pragma unroll
  for (int pass = 0; pass < 8; ++pass) {
    int kc = pass * 4 + kcl;
    int k = kc * 32 + oct * 8;
    short8 a8 = *(const short8*)(arow + k);
    short8 b8 = *(const short8*)(brow + k);
    short8 o;
#pragma unroll
    for (int e = 0; e < 8; ++e)
      o[e] = (short)f2bf(bf2f((unsigned short)a8[e]) * bf2f((unsigned short)b8[e]));
    *(short8*)(dst + kc * 1024) = o;
  }
  if (t < 128) {
    int kc = 32 + (t >> 6);
    int kpw = (t >> 6) * 32 + oct * 8;
    const float* prow = pw + (size_t)p * 64;
    float4 v0 = *(const float4*)(prow + kpw);
    float4 v1 = *(const float4*)(prow + kpw + 4);
    short8 o;
    o[0] = (short)f2bf(v0.x); o[1] = (short)f2bf(v0.y);
    o[2] = (short)f2bf(v0.z); o[3] = (short)f2bf(v0.w);
    o[4] = (short)f2bf(v1.x); o[5] = (short)f2bf(v1.y);
    o[6] = (short)f2bf(v1.z); o[7] = (short)f2bf(v1.w);
    *(short8*)(dst + kc * 1024) = o;
  }
}

// Wave-independent pre-packed GEMM, R10 block shape: 4 waves, each 64 rows,
// all sharing one 128-col B panel. 2-deep register ping-pong, no LDS/barriers.
// MODE 0: Ha+Hb fused (store to Hab; kcoff 32 for allm rows, 0 for am rows).
// MODE 1: main GEMM (Pt, kcoff 64, fused scorer epilogue -> partial).
template <int MODE>
__global__ __launch_bounds__(256, 2) void k_gt(
    const unsigned short* __restrict__ At, const unsigned short* __restrict__ BtAll,
    float* __restrict__ C, float* __restrict__ partial,
    const float* __restrict__ Hab, const float* __restrict__ b1,
    const float* __restrict__ Wout, const int* __restrict__ idx) {
  constexpr int NKC = MODE ? 34 : 32;
  constexpr int A_STRIDE = MODE ? PT_STRIDE : MT_STRIDE;
  int tid = threadIdx.x, lane = tid & 63, wave = tid >> 6;
  int llo = lane & 15, lhi = lane >> 4;
  int id = blockIdx.x;
  int x, y;
  if (MODE == 1) {
    int r = id >> 3;
    x = (id & 7) * 25 + (r >> 3);  // 200 x-blocks, 25 per XCD
    y = r & 7;
  } else {
    x = id >> 3;                   // 36 x-blocks
    y = id & 7;
  }
  int kcoff = MODE ? 64 : ((x < 32) ? 32 : 0);
  int row0 = x * 256 + wave * 64;
  int n0 = y * 128;
  const char* pa = (const char*)At + (size_t)(row0 >> 4) * A_STRIDE + lane * 16;
  const char* pb = (const char*)BtAll + (size_t)(n0 >> 4) * BT_STRIDE +
                   (size_t)kcoff * 1024 + lane * 16;

  f32x4 acc[4][8] = {};
  short8 aA[4], bA[8], aB[4], bB[8];
#pragma unroll
  for (int m = 0; m < 4; ++m) aA[m] = *(const short8*)(pa + (size_t)m * A_STRIDE);
#pragma unroll
  for (int n = 0; n < 8; ++n) bA[n] = *(const short8*)(pb + (size_t)n * BT_STRIDE);
  for (int kt = 0; kt < NKC; kt += 2) {
#pragma unroll
    for (int m = 0; m < 4; ++m)
      aB[m] = *(const short8*)(pa + (size_t)m * A_STRIDE + (kt + 1) * 1024);
#pragma unroll
    for (int n = 0; n < 8; ++n)
      bB[n] = *(const short8*)(pb + (size_t)n * BT_STRIDE + (kt + 1) * 1024);
#pragma unroll
    for (int m = 0; m < 4; ++m)
#pragma unroll
      for (int n = 0; n < 8; ++n)
        acc[m][n] = __builtin_amdgcn_mfma_f32_16x16x32_bf16(aA[m], bA[n], acc[m][n], 0, 0, 0);
    if (kt + 2 < NKC) {
#pragma unroll
      for (int m = 0; m < 4; ++m)
        aA[m] = *(const short8*)(pa + (size_t)m * A_STRIDE + (kt + 2) * 1024);
#pragma unroll
      for (int n = 0; n < 8; ++n)
        bA[n] = *(const short8*)(pb + (size_t)n * BT_STRIDE + (kt + 2) * 1024);
    }
#pragma unroll
    for (int m = 0; m < 4; ++m)
#pragma unroll
      for (int n = 0; n < 8; ++n)
        acc[m][n] = __builtin_amdgcn_mfma_f32_16x16x32_bf16(aB[m], bB[n], acc[m][n], 0, 0, 0);
  }

  if (MODE == 0) {
#pragma unroll
    for (int m = 0; m < 4; ++m)
#pragma unroll
      for (int i = 0; i < 4; ++i) {
        int row = row0 + m * 16 + lhi * 4 + i;
#pragma unroll
        for (int n = 0; n < 8; ++n)
          C[(size_t)row * 1024 + n0 + n * 16 + llo] = acc[m][n][i];
      }
  } else {
    float b1v[8], wov[8];
    int coln[8];
#pragma unroll
    for (int n = 0; n < 8; ++n) {
      coln[n] = n0 + n * 16 + llo;
      b1v[n] = b1[coln[n]];
      wov[n] = Wout[coln[n]];
    }
#pragma unroll
    for (int m = 0; m < 4; ++m)
#pragma unroll
      for (int i = 0; i < 4; ++i) {
        int p = row0 + m * 16 + lhi * 4 + i;
        int bb = p / 50;
        int gg = idx[p];
        const float* Har = Hab + (size_t)(8192 + bb) * 1024;
        const float* Hbr = Hab + (size_t)gg * 1024;
        float s0 = 0.f, s1 = 0.f;
#pragma unroll
        for (int n = 0; n < 4; ++n) {
          float h = acc[m][n][i] + Har[coln[n]] + Hbr[coln[n]] + b1v[n];
          h = h > 0.f ? h : 0.01f * h;
          s0 += h * wov[n];
        }
#pragma unroll
        for (int n = 4; n < 8; ++n) {
          float h = acc[m][n][i] + Har[coln[n]] + Hbr[coln[n]] + b1v[n];
          h = h > 0.f ? h : 0.01f * h;
          s1 += h * wov[n];
        }
        s0 += __shfl_xor(s0, 1, 64);
        s0 += __shfl_xor(s0, 2, 64);
        s0 += __shfl_xor(s0, 4, 64);
        s0 += __shfl_xor(s0, 8, 64);
        s1 += __shfl_xor(s1, 1, 64);
        s1 += __shfl_xor(s1, 2, 64);
        s1 += __shfl_xor(s1, 4, 64);
        s1 += __shfl_xor(s1, 8, 64);
        if (llo == 0) {
          partial[(size_t)p * 16 + y * 2 + 0] = s0;
          partial[(size_t)p * 16 + y * 2 + 1] = s1;
        }
      }
  }
}

__global__ void k_final(const float* __restrict__ partial, const float* __restrict__ rough,
                        const float* __restrict__ bout, float* __restrict__ out) {
  int t = blockIdx.x * 256 + threadIdx.x;
  if (t < 51200) {
    float s = rough[t] + bout[0];
    const float* pp = partial + (size_t)t * 16;
#pragma unroll
    for (int c = 0; c < 16; ++c) s += pp[c];
    out[(size_t)(t / 50) * 51 + 1 + (t % 50)] = s;
  }
  if (t < 1024) out[(size_t)t * 51] = 1e-7f;
}

extern "C" void kernel_launch(void* const* d_in, const int* in_sizes, int n_in,
                              void* d_out, int out_size, void* d_ws, size_t ws_size,
                              hipStream_t stream) {
  (void)in_sizes; (void)n_in; (void)out_size;
  const float* allm  = (const float*)d_in[0];  // [8192][1024]
  const float* am    = (const float*)d_in[1];  // [1024][1024]
  const float* pw    = (const float*)d_in[2];  // [1024][50][64]
  const float* rough = (const float*)d_in[3];  // [1024][50]
  const float* W1    = (const float*)d_in[4];  // [3136][1024]
  const float* b1    = (const float*)d_in[5];  // [1024]
  const float* Wout  = (const float*)d_in[6];  // [1024]
  const float* bout  = (const float*)d_in[7];  // [1]
  const int*   idx   = (const int*)d_in[8];    // [1024][50]
  float* out = (float*)d_out;                  // [1024][51]

  char* w = (char*)d_ws;
  unsigned short* BtAll = (unsigned short*)w; w += (size_t)64 * BT_STRIDE;
  unsigned short* Mt    = (unsigned short*)w; w += (size_t)576 * MT_STRIDE;
  unsigned short* Abm   = (unsigned short*)w; w += (size_t)1024 * 1024 * 2;
  unsigned short* Aball = (unsigned short*)w; w += (size_t)8192 * 1024 * 2;
  unsigned short* Pt    = (unsigned short*)w; w += (size_t)3200 * PT_STRIDE;
  float* Hab            = (float*)w;          w += (size_t)9216 * 1024 * 4;
  float* part           = (float*)w;          w += (size_t)51200 * 16 * 4;
  size_t need = (size_t)(w - (char*)d_ws);
  if (ws_size < need) return;

  k_packW<<<dim3(49, 16), 256, 0, stream>>>(W1, BtAll);
  k_cvt<<<dim3(1024), 256, 0, stream>>>(am, Abm, 1024 * 1024 / 4);
  k_cvt<<<dim3(8192), 256, 0, stream>>>(allm, Aball, 8192 * 1024 / 4);
  k_packM<<<dim3(576), 256, 0, stream>>>(am, allm, Mt);
  k_pairs<<<dim3(3200), 256, 0, stream>>>(Abm, Aball, pw, idx, Pt);
  // Ha+Hb fused: 9216 rows -> 36 x-blocks * 8 y = 288 blocks
  k_gt<0><<<dim3(288), 256, 0, stream>>>(Mt, BtAll, Hab, nullptr,
                                         nullptr, nullptr, nullptr, nullptr);
  // main: 51200 rows -> 200 x * 8 y = 1600 blocks, XCD swizzle
  k_gt<1><<<dim3(1600), 256, 0, stream>>>(Pt, BtAll, nullptr, part,
                                          Hab, b1, Wout, idx);
  k_final<<<dim3(200), 256, 0, stream>>>(part, rough, bout, out);
}